// Round 8
// baseline (175.638 us; speedup 1.0000x reference)
//
#include <hip/hip_runtime.h>
#include <math.h>

#define BB   16
#define CC   4
#define HH   640
#define WW   640
#define HWSZ (HH*WW)        // 409600 pixels per image
#define KM   16             // labels 1..16; 0 = background (derived)
#define NSUM (KM*CC)        // 64 channel-sum slots per image
#define NACC (NSUM+KM)      // + 16 counts = 80 ws floats per image
#define SIGMA_D 3.0f

#define GXB  200            // blocks per image -> 3200 blocks total
#define GPB  (HWSZ/4/GXB)   // 512 int4-groups per block
#define NIT  (GPB/64)       // 8 wave-iterations, compile-time constant

// ---------------------------------------------------------------------------
// Kernel 1: per-(image,label) channel sums + counts.
// CHANNEL-SPLIT register histogram, barrier-free A/B pipeline.
// Lesson r7: label-split made all 4 waves re-read all 5 arrays -> 524 MB
// lane-delivered = 6.3 TB/s path ceiling = 83us. Channel-split: wave w reads
// labels + ONLY pred channel w -> pred read once chip-wide, labels re-read
// 4x but L2-hit (same-block concurrent). 210 MB lane-delivered, 131 MB
// unique. Per thread: 16 label accs (own channel) + 4 counts (labels
// w*4+1..w*4+4), all statically indexed (r1/r2: runtime idx spills).
// No __syncthreads in loop (r6: lockstep bursts duty-cycle the memory).
// grid = (GXB, B), block = 256, 8 iters/wave exactly.
// ---------------------------------------------------------------------------
__global__ __launch_bounds__(256, 8) void seg_kernel(
    const float* __restrict__ pred, const int* __restrict__ labels,
    float* __restrict__ ws)
{
    const int b    = blockIdx.y;
    const int t    = threadIdx.x;
    const int lane = t & 63;
    const int w    = t >> 6;             // wave 0..3 = channel w
    const int cb   = w * 4 + 1;          // this wave's count labels: cb..cb+3

    const int4*   lab4 = (const int4*)(labels + (size_t)b * HWSZ);
    const float4* pw   = (const float4*)(pred + ((size_t)b * CC + w) * HWSZ);

    const int G0 = blockIdx.x * GPB + lane;   // this block's group window

    float acc[KM];                       // [label], this wave's channel
    float cnt[4];                        // counts for labels cb..cb+3
    #pragma unroll
    for (int k = 0; k < KM; ++k) acc[k] = 0.f;
    #pragma unroll
    for (int kk = 0; kk < 4; ++kk) cnt[kk] = 0.f;

    // one pixel: select-add into the matching label slot; 4 count adds
#define PIXEL(LB, X)                                                \
    {                                                               \
        const int   lbv = (LB);                                     \
        const float xv  = (X);                                      \
        _Pragma("unroll")                                           \
        for (int k = 0; k < KM; ++k)                                \
            acc[k] += (lbv == k + 1) ? xv : 0.f;                    \
        _Pragma("unroll")                                           \
        for (int kk = 0; kk < 4; ++kk)                              \
            cnt[kk] += (lbv == cb + kk) ? 1.f : 0.f;                \
    }

#define COMPUTE(L, Q)                                               \
    PIXEL((L).x, (Q).x);                                            \
    PIXEL((L).y, (Q).y);                                            \
    PIXEL((L).z, (Q).z);                                            \
    PIXEL((L).w, (Q).w);

    // software pipeline: named A/B register stages, 1-deep prefetch.
    int4   LA = lab4[G0];
    float4 QA = pw[G0];
    int4   LBv;
    float4 QB;

    #pragma unroll
    for (int it = 0; it < 3; ++it) {           // pairs (0,1) (2,3) (4,5)
        const int gB = G0 + (2 * it + 1) * 64;
        LBv = lab4[gB]; QB = pw[gB];
        COMPUTE(LA, QA);
        const int gA = G0 + (2 * it + 2) * 64;
        LA = lab4[gA]; QA = pw[gA];
        COMPUTE(LBv, QB);
    }
    {                                          // iterations 6, 7
        const int gB = G0 + 7 * 64;
        LBv = lab4[gB]; QB = pw[gB];
        COMPUTE(LA, QA);
        COMPUTE(LBv, QB);
    }

    // wave butterfly reduce (static indices), lane 0 scatters to ws.
    // wave w's acc[k] -> ws[b*NACC + k*4 + w]; cnt[kk] -> ws[.. NSUM + cb-1+kk]
    #pragma unroll
    for (int k = 0; k < KM; ++k) {
        float v = acc[k];
        v += __shfl_xor(v, 1);  v += __shfl_xor(v, 2);
        v += __shfl_xor(v, 4);  v += __shfl_xor(v, 8);
        v += __shfl_xor(v, 16); v += __shfl_xor(v, 32);
        acc[k] = v;
    }
    #pragma unroll
    for (int kk = 0; kk < 4; ++kk) {
        float v = cnt[kk];
        v += __shfl_xor(v, 1);  v += __shfl_xor(v, 2);
        v += __shfl_xor(v, 4);  v += __shfl_xor(v, 8);
        v += __shfl_xor(v, 16); v += __shfl_xor(v, 32);
        cnt[kk] = v;
    }

    if (lane == 0) {
        float* wsb = ws + b * NACC;
        #pragma unroll
        for (int k = 0; k < KM; ++k)
            atomicAdd(&wsb[k * 4 + w], acc[k]);
        #pragma unroll
        for (int kk = 0; kk < 4; ++kk)
            atomicAdd(&wsb[NSUM + (cb - 1) + kk], cnt[kk]);
    }
#undef PIXEL
#undef COMPUTE
}

// ---------------------------------------------------------------------------
// Kernel 2: tiny epilogue — N, f, sum_g, Kb, own/other/scale, scalar out.
// ---------------------------------------------------------------------------
__global__ void finalize_kernel(const float* __restrict__ ws, float* __restrict__ out)
{
    __shared__ float s_sumg[BB], s_P[BB], s_Kb[BB];
    const float F0 = logf(SIGMA_D * SIGMA_D + 1.0f);   // log(10)
    int b = threadIdx.x;
    if (b < BB) {
        const float* w = ws + b * NACC;
        float cnt_sum = 0.f, sum_g = 0.f, Kb = 0.f;
        for (int k = 1; k <= KM; ++k) {
            float s0 = w[(k-1)*4+0], s1 = w[(k-1)*4+1];
            float s2 = w[(k-1)*4+2], s3 = w[(k-1)*4+3];
            float cn = w[NSUM + (k-1)];
            float N  = sqrtf(s0*s0 + s1*s1 + s2*s2 + s3*s3);
            float r  = fmaxf(SIGMA_D - N, 0.f);
            float f  = logf(r*r + 1.0f);
            sum_g   += cn * f;
            cnt_sum += cn;
            if (cn > 0.f) Kb = (float)k;
        }
        float c0 = (float)HWSZ - cnt_sum;     // background count
        sum_g += c0 * F0;
        s_sumg[b] = sum_g;
        s_Kb[b]   = Kb;
        s_P[b]    = (Kb > 1.f) ? Kb * (Kb - 1.f) * 0.5f : 0.f;  // P_act
    }
    __syncthreads();
    if (threadIdx.x == 0) {
        double sumP = 0.0;
        for (int i = 0; i < BB; ++i) sumP += (double)s_P[i];
        double total = 0.0;
        for (int i = 0; i < BB; ++i) {
            double Kb   = (double)s_Kb[i];
            double Pact = (double)s_P[i];
            double own  = 0.0;
            if (Kb > 1.0)
                own = (Kb - 1.0) * (double)s_sumg[i]
                    + (double)HWSZ * (Pact - (Kb - 1.0)) * (double)F0;
            double other = (sumP - Pact) * (double)HWSZ * (double)F0;
            double scale = (Kb > 1.0) ? 1.0 / (Kb * (Kb - 1.0)) : Kb;
            total += scale * (own + other);
        }
        out[0] = (float)total;
    }
}

// ---------------------------------------------------------------------------
extern "C" void kernel_launch(void* const* d_in, const int* in_sizes, int n_in,
                              void* d_out, int out_size, void* d_ws, size_t ws_size,
                              hipStream_t stream)
{
    const float* pred   = (const float*)d_in[0];
    const int*   labels = (const int*)d_in[1];
    float*       out    = (float*)d_out;
    float*       ws     = (float*)d_ws;

    hipMemsetAsync(ws, 0, BB * NACC * sizeof(float), stream);

    dim3 grid(GXB, BB);
    seg_kernel<<<grid, 256, 0, stream>>>(pred, labels, ws);
    finalize_kernel<<<1, 64, 0, stream>>>(ws, out);
}

// Round 9
// 46.775 us; speedup vs baseline: 3.7549x; 3.7549x over previous
//
#include <hip/hip_runtime.h>
#include <math.h>

#define BB   16
#define CC   4
#define HH   640
#define WW   640
#define HWSZ (HH*WW)        // 409600 pixels per image
#define KM   16             // labels 1..16; 0 = background (derived)
#define NSUM (KM*CC)        // 64 channel-sum slots per image
#define NACC (NSUM+KM)      // + 16 counts = 80 slots per (image, block)
#define SIGMA_D 3.0f

#define GXB  64             // blocks per image -> 1024 blocks total (4/CU)
#define GPB  (HWSZ/4/GXB)   // 1600 int4-groups per block
#define NIT  (GPB/64)       // 25 wave-iterations, compile-time constant

// ---------------------------------------------------------------------------
// Kernel 1: per-(image,label) channel sums + counts.
// r7's proven register scan (label-split, barrier-free A/B pipeline) with an
// ATOMIC-FREE epilogue. Lesson r8 (+r5/r6/r7 regression line): dur ~= 28us
// + 0.67us/Katomic -- the 80 contended ws cache lines bounced across 8 XCDs
// dominate everything; steady-state HBM traffic was pure atomic writeback.
// Here each block stores its 80 partials to a PRIVATE slice (no contention,
// no memset); finalize reduces 64 partials/image deterministically.
// Other locked-in lessons: runtime-indexed register arrays spill (r1/r2);
// LDS atomics ~224cyc/inst regardless of conflicts (r3/r4); barrier-gated
// tiles duty-cycle memory (r6).
// grid = (GXB, B), block = 256.
// ---------------------------------------------------------------------------
__global__ __launch_bounds__(256) void seg_kernel(
    const float* __restrict__ pred, const int* __restrict__ labels,
    float* __restrict__ part)
{
    const int b     = blockIdx.y;
    const int t     = threadIdx.x;
    const int lane  = t & 63;
    const int w     = t >> 6;            // wave 0..3
    const int kbase = w * 4 + 1;         // this wave's labels

    const int4*   lab4 = (const int4*)(labels + (size_t)b * HWSZ);
    const float4* p0   = (const float4*)(pred + ((size_t)b * CC + 0) * HWSZ);
    const float4* p1   = (const float4*)(pred + ((size_t)b * CC + 1) * HWSZ);
    const float4* p2   = (const float4*)(pred + ((size_t)b * CC + 2) * HWSZ);
    const float4* p3   = (const float4*)(pred + ((size_t)b * CC + 3) * HWSZ);

    const int G0 = blockIdx.x * GPB + lane;   // this block's group window

    float acc[4][4];                     // [label][channel], static idx only
    float cnt[4];
    #pragma unroll
    for (int kk = 0; kk < 4; ++kk) {
        cnt[kk] = 0.f;
        #pragma unroll
        for (int c = 0; c < CC; ++c) acc[kk][c] = 0.f;
    }

#define PIXEL(LB, X0, X1, X2, X3)                                   \
    {                                                               \
        const int lbv = (LB);                                       \
        _Pragma("unroll")                                           \
        for (int kk = 0; kk < 4; ++kk) {                            \
            float m = (lbv == kbase + kk) ? 1.0f : 0.0f;            \
            acc[kk][0] = fmaf(m, (X0), acc[kk][0]);                 \
            acc[kk][1] = fmaf(m, (X1), acc[kk][1]);                 \
            acc[kk][2] = fmaf(m, (X2), acc[kk][2]);                 \
            acc[kk][3] = fmaf(m, (X3), acc[kk][3]);                 \
            cnt[kk]   += m;                                         \
        }                                                           \
    }

#define COMPUTE(L, Q0, Q1, Q2, Q3)                                  \
    PIXEL((L).x, (Q0).x, (Q1).x, (Q2).x, (Q3).x);                   \
    PIXEL((L).y, (Q0).y, (Q1).y, (Q2).y, (Q3).y);                   \
    PIXEL((L).z, (Q0).z, (Q1).z, (Q2).z, (Q3).z);                   \
    PIXEL((L).w, (Q0).w, (Q1).w, (Q2).w, (Q3).w);

    // software pipeline: named A/B register stages, 1-deep prefetch.
    int4   LA = lab4[G0];
    float4 A0 = p0[G0], A1 = p1[G0], A2 = p2[G0], A3 = p3[G0];
    int4   LBv;
    float4 B0, B1, B2, B3;

    #pragma unroll
    for (int it = 0; it < (NIT - 1) / 2; ++it) {       // 12 double-steps
        const int gB = G0 + (2 * it + 1) * 64;
        LBv = lab4[gB]; B0 = p0[gB]; B1 = p1[gB]; B2 = p2[gB]; B3 = p3[gB];
        COMPUTE(LA, A0, A1, A2, A3);
        const int gA = G0 + (2 * it + 2) * 64;
        LA = lab4[gA]; A0 = p0[gA]; A1 = p1[gA]; A2 = p2[gA]; A3 = p3[gA];
        COMPUTE(LBv, B0, B1, B2, B3);
    }
    COMPUTE(LA, A0, A1, A2, A3);                       // iteration 24

    // wave butterfly reduce (static indices), lane 0 stores 20 disjoint
    // slots to this block's PRIVATE partial slice (plain stores, no atomics)
    #pragma unroll
    for (int kk = 0; kk < 4; ++kk) {
        #pragma unroll
        for (int c = 0; c < CC; ++c) {
            float v = acc[kk][c];
            v += __shfl_xor(v, 1);  v += __shfl_xor(v, 2);
            v += __shfl_xor(v, 4);  v += __shfl_xor(v, 8);
            v += __shfl_xor(v, 16); v += __shfl_xor(v, 32);
            acc[kk][c] = v;
        }
        float v = cnt[kk];
        v += __shfl_xor(v, 1);  v += __shfl_xor(v, 2);
        v += __shfl_xor(v, 4);  v += __shfl_xor(v, 8);
        v += __shfl_xor(v, 16); v += __shfl_xor(v, 32);
        cnt[kk] = v;
    }

    if (lane == 0) {
        float* pb = part + ((size_t)b * GXB + blockIdx.x) * NACC;
        #pragma unroll
        for (int kk = 0; kk < 4; ++kk) {
            const int kidx = kbase - 1 + kk;   // 0..15, disjoint across waves
            #pragma unroll
            for (int c = 0; c < CC; ++c)
                pb[kidx * 4 + c] = acc[kk][c];
            pb[NSUM + kidx] = cnt[kk];
        }
    }
#undef PIXEL
#undef COMPUTE
}

// ---------------------------------------------------------------------------
// Kernel 2: reduce 64 partials per (image, slot), then the scalar epilogue.
// ---------------------------------------------------------------------------
__global__ __launch_bounds__(256) void finalize_kernel(
    const float* __restrict__ part, float* __restrict__ out)
{
    __shared__ float red[BB * NACC];          // 1280 floats
    __shared__ float s_sumg[BB], s_P[BB], s_Kb[BB];
    const float F0 = logf(SIGMA_D * SIGMA_D + 1.0f);   // log(10)
    const int t = threadIdx.x;

    // stage 1: deterministic sum over the GXB per-block partials
    for (int s = t; s < BB * NACC; s += 256) {
        const int b   = s / NACC;
        const int idx = s - b * NACC;
        float v = 0.f;
        #pragma unroll 8
        for (int gx = 0; gx < GXB; ++gx)
            v += part[((size_t)b * GXB + gx) * NACC + idx];
        red[s] = v;
    }
    __syncthreads();

    // stage 2: per-image math
    if (t < BB) {
        const float* w = red + t * NACC;
        float cnt_sum = 0.f, sum_g = 0.f, Kb = 0.f;
        for (int k = 1; k <= KM; ++k) {
            float s0 = w[(k-1)*4+0], s1 = w[(k-1)*4+1];
            float s2 = w[(k-1)*4+2], s3 = w[(k-1)*4+3];
            float cn = w[NSUM + (k-1)];
            float N  = sqrtf(s0*s0 + s1*s1 + s2*s2 + s3*s3);
            float r  = fmaxf(SIGMA_D - N, 0.f);
            float f  = logf(r*r + 1.0f);
            sum_g   += cn * f;
            cnt_sum += cn;
            if (cn > 0.f) Kb = (float)k;
        }
        float c0 = (float)HWSZ - cnt_sum;     // background count
        sum_g += c0 * F0;
        s_sumg[t] = sum_g;
        s_Kb[t]   = Kb;
        s_P[t]    = (Kb > 1.f) ? Kb * (Kb - 1.f) * 0.5f : 0.f;  // P_act
    }
    __syncthreads();

    // stage 3: cross-image combine
    if (t == 0) {
        double sumP = 0.0;
        for (int i = 0; i < BB; ++i) sumP += (double)s_P[i];
        double total = 0.0;
        for (int i = 0; i < BB; ++i) {
            double Kb   = (double)s_Kb[i];
            double Pact = (double)s_P[i];
            double own  = 0.0;
            if (Kb > 1.0)
                own = (Kb - 1.0) * (double)s_sumg[i]
                    + (double)HWSZ * (Pact - (Kb - 1.0)) * (double)F0;
            double other = (sumP - Pact) * (double)HWSZ * (double)F0;
            double scale = (Kb > 1.0) ? 1.0 / (Kb * (Kb - 1.0)) : Kb;
            total += scale * (own + other);
        }
        out[0] = (float)total;
    }
}

// ---------------------------------------------------------------------------
extern "C" void kernel_launch(void* const* d_in, const int* in_sizes, int n_in,
                              void* d_out, int out_size, void* d_ws, size_t ws_size,
                              hipStream_t stream)
{
    const float* pred   = (const float*)d_in[0];
    const int*   labels = (const int*)d_in[1];
    float*       out    = (float*)d_out;
    float*       part   = (float*)d_ws;       // 16*64*80*4 B = 328 KB scratch

    dim3 grid(GXB, BB);
    seg_kernel<<<grid, 256, 0, stream>>>(pred, labels, part);
    finalize_kernel<<<1, 256, 0, stream>>>(part, out);
}